// Round 9
// baseline (450.124 us; speedup 1.0000x reference)
//
#include <hip/hip_runtime.h>

#define NSEG 8192           // faces per set
#define NPTS (3 * NSEG)     // 24576 unified points [S | T | R]
#define NSUP 192            // 128-point super-tiles (64 per segment)
#define NYG  25             // y-groups: g=0..23 -> y=4g..4g+3; g=24 -> y=96

typedef short bf16x8 __attribute__((ext_vector_type(8)));   // 8 bf16 (4 VGPRs)
typedef float f32x4  __attribute__((ext_vector_type(4)));   // 4 fp32 acc
typedef unsigned short u16;

__device__ __forceinline__ u16 f2bf(float x) {              // RNE f32 -> bf16 bits
    unsigned u = __builtin_bit_cast(unsigned, x);
    return (u16)((u + 0x7FFFu + ((u >> 16) & 1u)) >> 16);
}
__device__ __forceinline__ float bf2f(u16 h) {
    unsigned u = ((unsigned)h) << 16;
    return __builtin_bit_cast(float, u);
}

__device__ __forceinline__ void compute_point(
    int seg, int f,
    const float* __restrict__ sv, const int* __restrict__ si,
    const float* __restrict__ tv, const int* __restrict__ ti,
    const float* __restrict__ rn, const float* __restrict__ rc,
    float& cx, float& cy, float& cz, float& nx, float& ny, float& nz)
{
    if (seg == 2) {
        nx = rn[3*f];   ny = rn[3*f+1]; nz = rn[3*f+2];
        cx = rc[3*f];   cy = rc[3*f+1]; cz = rc[3*f+2];
    } else {
        const float* v  = (seg == 0) ? sv : tv;
        const int*   nd = (seg == 0) ? si : ti;
        int i0 = nd[3*f], i1 = nd[3*f+1], i2 = nd[3*f+2];
        float ax = v[3*i0], ay = v[3*i0+1], az = v[3*i0+2];
        float bx = v[3*i1], by = v[3*i1+1], bz = v[3*i1+2];
        float gx = v[3*i2], gy = v[3*i2+1], gz = v[3*i2+2];
        float ux = ax-bx, uy = ay-by, uz = az-bz;
        float wx = gx-bx, wy = gy-by, wz = gz-bz;
        nx = 0.5f*(uy*wz - uz*wy);
        ny = 0.5f*(uz*wx - ux*wz);
        nz = 0.5f*(ux*wy - uy*wx);
        cx = (ax+bx+gx)*(1.0f/3.0f);
        cy = (ay+by+gy)*(1.0f/3.0f);
        cz = (az+bz+gz)*(1.0f/3.0f);
    }
}

// Feature rows (K=16 bf16), hi/lo split: t = A_t . B_t = 1+|ci-cj|^2 (~1e-3 abs err).
// Records: A-point = {at[16], an[16]} (64 B = 4 bf16x8 frags), B-point = {bt[16], bn[16]}.
// For 16x16x32 MFMA these are quads q=0,1 (k=0..15); q=2,3 (k=16..31) are zeros held
// in-register by the energy kernel (masked loads), so no padding is stored.
__global__ void setup_feats(const float* __restrict__ sv, const int* __restrict__ si,
                            const float* __restrict__ tv, const int* __restrict__ ti,
                            const float* __restrict__ rn, const float* __restrict__ rc,
                            u16* __restrict__ ws, float* __restrict__ out) {
    int p = blockIdx.x * 256 + threadIdx.x;
    if (p == 0) out[0] = 0.0f;          // d_out poisoned 0xAA before every launch
    if (p >= NPTS) return;
    int seg = p >> 13, f = p & (NSEG - 1);
    float cx, cy, cz, nx, ny, nz;
    compute_point(seg, f, sv, si, tv, ti, rn, rc, cx, cy, cz, nx, ny, nz);

    const u16 ONE = 0x3F80;
    float s = cx*cx + cy*cy + cz*cz;
    u16 chx = f2bf(cx), chy = f2bf(cy), chz = f2bf(cz);
    u16 clx = f2bf(cx - bf2f(chx)), cly = f2bf(cy - bf2f(chy)), clz = f2bf(cz - bf2f(chz));
    u16 sh  = f2bf(s);
    u16 sl  = f2bf(s - bf2f(sh));
    u16 m2hx = f2bf(-2.0f*bf2f(chx)), m2hy = f2bf(-2.0f*bf2f(chy)), m2hz = f2bf(-2.0f*bf2f(chz));
    u16 m2lx = f2bf(-2.0f*bf2f(clx)), m2ly = f2bf(-2.0f*bf2f(cly)), m2lz = f2bf(-2.0f*bf2f(clz));
    u16 nhx = f2bf(nx), nhy = f2bf(ny), nhz = f2bf(nz);
    u16 nlx = f2bf(nx - bf2f(nhx)), nly = f2bf(ny - bf2f(nhy)), nlz = f2bf(nz - bf2f(nhz));

    u16 at[16] = {chx,chy,chz, clx,cly,clz, chx,chy,chz, sh, sl, ONE, ONE, ONE, 0, 0};
    u16 bt[16] = {m2hx,m2hy,m2hz, m2hx,m2hy,m2hz, m2lx,m2ly,m2lz, ONE, ONE, sh, sl, ONE, 0, 0};
    u16 an[16] = {nhx,nhy,nhz, nlx,nly,nlz, nhx,nhy,nhz, 0,0,0,0,0,0,0};
    u16 bn[16] = {nhx,nhy,nhz, nhx,nhy,nhz, nlx,nly,nlz, 0,0,0,0,0,0,0};

    bf16x8* A8 = (bf16x8*)ws;            // A-record: frags [at0 at1 an0 an1] per point
    bf16x8* B8 = A8 + (size_t)NPTS*4;    // B-record: frags [bt0 bt1 bn0 bn1] per point
    bf16x8 v0, v1, v2, v3;
    #pragma unroll
    for (int k = 0; k < 8; ++k) { v0[k] = (short)at[k]; v1[k] = (short)at[k+8];
                                  v2[k] = (short)an[k]; v3[k] = (short)an[k+8]; }
    A8[(size_t)p*4+0] = v0; A8[(size_t)p*4+1] = v1; A8[(size_t)p*4+2] = v2; A8[(size_t)p*4+3] = v3;
    #pragma unroll
    for (int k = 0; k < 8; ++k) { v0[k] = (short)bt[k]; v1[k] = (short)bt[k+8];
                                  v2[k] = (short)bn[k]; v3[k] = (short)bn[k+8]; }
    B8[(size_t)p*4+0] = v0; B8[(size_t)p*4+1] = v1; B8[(size_t)p*4+2] = v2; B8[(size_t)p*4+3] = v3;
}

// Symmetric-pair kernel over 128-pt super-tiles (16x16x32 MFMA, 4-reg accumulators
// to escape R7's AGPR-pressure occupancy cap).
// Wrapped map: block (X,g) handles y in {4g..4g+3} (g<24) or {96} (g=24);
// (I,J) = (X, (X+y)%192); mult = 2 except y==0 (diag, once) and y==96 (hit twice).
// Effective super-pairs: 192 + 192 + 192*95*2 = 192^2. ✓
// Per block: 4 waves x 32 i-rows (two 16-row i-tiles sharing B frags); 8 j-tiles of 16
// per y. Lanes 32..63 (quads 2,3 = k 16..31) carry zero frags: masked loads write
// lanes<32 only, upper lanes stay zero from the one-time init.
__launch_bounds__(256, 6)
__global__ void energy_mfma(const u16* __restrict__ ws, float* __restrict__ out) {
    const int tid  = threadIdx.x;
    const int lane = tid & 63, wid = tid >> 6;
    const int n16  = lane & 15, q = (lane >> 4) & 1;
    const bool lo  = lane < 32;              // quads 0,1 = real k 0..15; else zeros

    const int X = blockIdx.x;                // 0..191
    const int g = blockIdx.y;                // 0..24
    const int y0 = 4*g;
    const int cnt = (g == 24) ? 1 : 4;
    const int gi = X >> 6;                   // 64 super-tiles per segment

    const float Wt[9] = {1.8f, -0.8f, -1.0f,
                        -0.8f,  1.8f, -1.0f,
                        -1.0f, -1.0f,  2.0f};

    const bf16x8* A8 = (const bf16x8*)ws;
    const bf16x8* B8 = A8 + (size_t)NPTS*4;

    // two persistent 16-row i-tiles per wave: rows X*128 + wid*32 + {0,16} + n16
    bf16x8 at0, an0, at1, an1;
    #pragma unroll
    for (int k = 0; k < 8; ++k) { at0[k] = 0; an0[k] = 0; at1[k] = 0; an1[k] = 0; }
    const int pi = X*128 + wid*32 + n16;
    if (lo) {
        at0 = A8[pi*4 + q];        an0 = A8[pi*4 + 2 + q];
        at1 = A8[(pi+16)*4 + q];   an1 = A8[(pi+16)*4 + 2 + q];
    }

    f32x4 Z = {0.0f, 0.0f, 0.0f, 0.0f};

    // double-buffered B frags; upper lanes permanently zero
    bf16x8 bT[2], bN[2];
    #pragma unroll
    for (int k = 0; k < 8; ++k) { bT[0][k] = 0; bT[1][k] = 0; bN[0][k] = 0; bN[1][k] = 0; }

    float acc = 0.0f;
    for (int yy = 0; yy < cnt; ++yy) {
        const int y = y0 + yy;
        int J = X + y; if (J >= NSUP) J -= NSUP;
        const float mult = (y == 0 || y == 96) ? 1.0f : 2.0f;
        const float w = Wt[gi*3 + (J >> 6)] * mult;

        const int bbase = (J*128 + n16)*4 + q;   // frag idx; j-tile stride = 16 pts * 4 = 64
        if (lo) { bT[0] = B8[bbase]; bN[0] = B8[bbase + 2]; }

        float ts0 = 0.0f, ts1 = 0.0f;
        #pragma unroll
        for (int jt = 0; jt < 8; ++jt) {
            const int cur = jt & 1, nxt = cur ^ 1;
            if (jt < 7 && lo) {
                bT[nxt] = B8[bbase + (jt+1)*64];
                bN[nxt] = B8[bbase + (jt+1)*64 + 2];
            }
            f32x4 ct0 = __builtin_amdgcn_mfma_f32_16x16x32_bf16(at0, bT[cur], Z, 0, 0, 0);
            f32x4 cn0 = __builtin_amdgcn_mfma_f32_16x16x32_bf16(an0, bN[cur], Z, 0, 0, 0);
            f32x4 ct1 = __builtin_amdgcn_mfma_f32_16x16x32_bf16(at1, bT[cur], Z, 0, 0, 0);
            f32x4 cn1 = __builtin_amdgcn_mfma_f32_16x16x32_bf16(an1, bN[cur], Z, 0, 0, 0);

            // batched rcp: one v_rcp per 4 pairs (each lane holds 4 (row,col) pairs)
            {
                float q0 = ct0[0]*ct0[0], q1 = ct0[1]*ct0[1];
                float q2 = ct0[2]*ct0[2], q3 = ct0[3]*ct0[3];
                float s01 = q0*q1, s23 = q2*q3;
                float r   = __builtin_amdgcn_rcpf(s01*s23);
                float u   = __builtin_fmaf(cn0[1], q0, cn0[0]*q1);
                float v   = __builtin_fmaf(cn0[3], q2, cn0[2]*q3);
                float num = __builtin_fmaf(v, s01, u*s23);
                ts0 = __builtin_fmaf(num, r, ts0);
            }
            {
                float q0 = ct1[0]*ct1[0], q1 = ct1[1]*ct1[1];
                float q2 = ct1[2]*ct1[2], q3 = ct1[3]*ct1[3];
                float s01 = q0*q1, s23 = q2*q3;
                float r   = __builtin_amdgcn_rcpf(s01*s23);
                float u   = __builtin_fmaf(cn1[1], q0, cn1[0]*q1);
                float v   = __builtin_fmaf(cn1[3], q2, cn1[2]*q3);
                float num = __builtin_fmaf(v, s01, u*s23);
                ts1 = __builtin_fmaf(num, r, ts1);
            }
        }
        acc = __builtin_fmaf(w, ts0 + ts1, acc);
    }

    // wave shuffle reduce -> 4 partials -> one atomic per block
    for (int off = 32; off; off >>= 1) acc += __shfl_down(acc, off, 64);
    __shared__ float partial[4];
    if ((tid & 63) == 0) partial[wid] = acc;
    __syncthreads();
    if (tid == 0)
        atomicAdd(out, (partial[0] + partial[1]) + (partial[2] + partial[3]));
}

extern "C" void kernel_launch(void* const* d_in, const int* in_sizes, int n_in,
                              void* d_out, int out_size, void* d_ws, size_t ws_size,
                              hipStream_t stream) {
    const float* sv = (const float*)d_in[0];
    const int*   si = (const int*)d_in[1];
    const float* tv = (const float*)d_in[2];
    const int*   ti = (const int*)d_in[3];
    const float* rn = (const float*)d_in[4];
    const float* rc = (const float*)d_in[5];
    float* out = (float*)d_out;
    u16*   ws  = (u16*)d_ws;                      // 2 x 24576 x 64 B = 3 MB features

    setup_feats<<<NPTS/256, 256, 0, stream>>>(sv, si, tv, ti, rn, rc, ws, out);
    dim3 grid(NSUP, NYG);                         // 192 x 25 = 4800 blocks
    energy_mfma<<<grid, 256, 0, stream>>>(ws, out);
}

// Round 10
// 133.763 us; speedup vs baseline: 3.3651x; 3.3651x over previous
//
#include <hip/hip_runtime.h>

#define NSEG 8192           // faces per set
#define NPTS (3 * NSEG)     // 24576 unified points [S | T | R]
#define NSUP 96             // 256-point super-tiles (32 per segment)
#define NY   49             // wrapped-triangular y-extent: grid 96 x 49 = 4704 blocks

typedef short bf16x8 __attribute__((ext_vector_type(8)));   // 8 bf16 (4 VGPRs)
typedef float f32x16 __attribute__((ext_vector_type(16)));  // 16 fp32 acc
typedef unsigned short u16;

__device__ __forceinline__ u16 f2bf(float x) {              // RNE f32 -> bf16 bits
    unsigned u = __builtin_bit_cast(unsigned, x);
    return (u16)((u + 0x7FFFu + ((u >> 16) & 1u)) >> 16);
}
__device__ __forceinline__ float bf2f(u16 h) {
    unsigned u = ((unsigned)h) << 16;
    return __builtin_bit_cast(float, u);
}

__device__ __forceinline__ void compute_point(
    int seg, int f,
    const float* __restrict__ sv, const int* __restrict__ si,
    const float* __restrict__ tv, const int* __restrict__ ti,
    const float* __restrict__ rn, const float* __restrict__ rc,
    float& cx, float& cy, float& cz, float& nx, float& ny, float& nz)
{
    if (seg == 2) {
        nx = rn[3*f];   ny = rn[3*f+1]; nz = rn[3*f+2];
        cx = rc[3*f];   cy = rc[3*f+1]; cz = rc[3*f+2];
    } else {
        const float* v  = (seg == 0) ? sv : tv;
        const int*   nd = (seg == 0) ? si : ti;
        int i0 = nd[3*f], i1 = nd[3*f+1], i2 = nd[3*f+2];
        float ax = v[3*i0], ay = v[3*i0+1], az = v[3*i0+2];
        float bx = v[3*i1], by = v[3*i1+1], bz = v[3*i1+2];
        float gx = v[3*i2], gy = v[3*i2+1], gz = v[3*i2+2];
        float ux = ax-bx, uy = ay-by, uz = az-bz;
        float wx = gx-bx, wy = gy-by, wz = gz-bz;
        nx = 0.5f*(uy*wz - uz*wy);
        ny = 0.5f*(uz*wx - ux*wz);
        nz = 0.5f*(ux*wy - uy*wx);
        cx = (ax+bx+gx)*(1.0f/3.0f);
        cy = (ay+by+gy)*(1.0f/3.0f);
        cz = (az+bz+gz)*(1.0f/3.0f);
    }
}

// Feature rows (K=16 bf16), hi/lo split: t = A_t . B_t = 1+|ci-cj|^2 (~1e-3 abs err).
// Interleaved records: A-side point = {at[16], an[16]} (64 B), B-side = {bt[16], bn[16]}.
__global__ void setup_feats(const float* __restrict__ sv, const int* __restrict__ si,
                            const float* __restrict__ tv, const int* __restrict__ ti,
                            const float* __restrict__ rn, const float* __restrict__ rc,
                            u16* __restrict__ ws, float* __restrict__ out) {
    int p = blockIdx.x * 256 + threadIdx.x;
    if (p == 0) out[0] = 0.0f;          // d_out poisoned 0xAA before every launch
    if (p >= NPTS) return;
    int seg = p >> 13, f = p & (NSEG - 1);
    float cx, cy, cz, nx, ny, nz;
    compute_point(seg, f, sv, si, tv, ti, rn, rc, cx, cy, cz, nx, ny, nz);

    const u16 ONE = 0x3F80;
    float s = cx*cx + cy*cy + cz*cz;
    u16 chx = f2bf(cx), chy = f2bf(cy), chz = f2bf(cz);
    u16 clx = f2bf(cx - bf2f(chx)), cly = f2bf(cy - bf2f(chy)), clz = f2bf(cz - bf2f(chz));
    u16 sh  = f2bf(s);
    u16 sl  = f2bf(s - bf2f(sh));
    u16 m2hx = f2bf(-2.0f*bf2f(chx)), m2hy = f2bf(-2.0f*bf2f(chy)), m2hz = f2bf(-2.0f*bf2f(chz));
    u16 m2lx = f2bf(-2.0f*bf2f(clx)), m2ly = f2bf(-2.0f*bf2f(cly)), m2lz = f2bf(-2.0f*bf2f(clz));
    u16 nhx = f2bf(nx), nhy = f2bf(ny), nhz = f2bf(nz);
    u16 nlx = f2bf(nx - bf2f(nhx)), nly = f2bf(ny - bf2f(nhy)), nlz = f2bf(nz - bf2f(nhz));

    u16 at[16] = {chx,chy,chz, clx,cly,clz, chx,chy,chz, sh, sl, ONE, ONE, ONE, 0, 0};
    u16 bt[16] = {m2hx,m2hy,m2hz, m2hx,m2hy,m2hz, m2lx,m2ly,m2lz, ONE, ONE, sh, sl, ONE, 0, 0};
    u16 an[16] = {nhx,nhy,nhz, nlx,nly,nlz, nhx,nhy,nhz, 0,0,0,0,0,0,0};
    u16 bn[16] = {nhx,nhy,nhz, nhx,nhy,nhz, nlx,nly,nlz, 0,0,0,0,0,0,0};

    bf16x8* A8 = (bf16x8*)ws;            // A-record: frags [at0 at1 an0 an1] per point
    bf16x8* B8 = A8 + (size_t)NPTS*4;    // B-record: frags [bt0 bt1 bn0 bn1] per point
    bf16x8 v0, v1, v2, v3;
    #pragma unroll
    for (int k = 0; k < 8; ++k) { v0[k] = (short)at[k]; v1[k] = (short)at[k+8];
                                  v2[k] = (short)an[k]; v3[k] = (short)an[k+8]; }
    A8[(size_t)p*4+0] = v0; A8[(size_t)p*4+1] = v1; A8[(size_t)p*4+2] = v2; A8[(size_t)p*4+3] = v3;
    #pragma unroll
    for (int k = 0; k < 8; ++k) { v0[k] = (short)bt[k]; v1[k] = (short)bt[k+8];
                                  v2[k] = (short)bn[k]; v3[k] = (short)bn[k+8]; }
    B8[(size_t)p*4+0] = v0; B8[(size_t)p*4+1] = v1; B8[(size_t)p*4+2] = v2; B8[(size_t)p*4+3] = v3;
}

// Symmetric-pair kernel (proven R7 map, R6 per-wave structure).
// Wrapped-rectangle over 256-pt super-tiles: block (X,Y): I=X, J=(X+Y)%96;
// mult = 2 except Y==0 (diagonal, full, once) and Y==48 (pair hit from both ends)
// -> effective super-pairs 96+96+96*47*2 = 96^2. ✓
// Block = 512 threads = 8 waves; each wave owns ONE 32-row i-tile (2 MFMA
// accumulators = 32 acc regs -> R6's 5.5-waves/SIMD occupancy, unlike R7's
// dual-tile 4-acc variant). All loads unconditional full-wave; prefetch in
// named registers (R8's masked loads + frag arrays caused scratch thrash).
__launch_bounds__(512, 3)
__global__ void energy_mfma(const u16* __restrict__ ws, float* __restrict__ out) {
    const int tid  = threadIdx.x;
    const int lane = tid & 63, wid = tid >> 6;      // 8 waves
    const int half = lane >> 5, r32 = lane & 31;

    const int X = blockIdx.x;                 // 0..95
    const int Y = blockIdx.y;                 // 0..48
    int J = X + Y; if (J >= NSUP) J -= NSUP;
    const int gi = X >> 5;                    // 32 super-tiles per segment
    const int gj = J >> 5;

    const float Wt[9] = {1.8f, -0.8f, -1.0f,
                        -0.8f,  1.8f, -1.0f,
                        -1.0f, -1.0f,  2.0f};
    const float mult = (Y == 0 || Y == 48) ? 1.0f : 2.0f;
    const float w = Wt[gi*3 + gj] * mult;     // block-uniform

    const bf16x8* A8 = (const bf16x8*)ws;
    const bf16x8* B8 = A8 + (size_t)NPTS*4;

    // one persistent 32-row i-tile per wave: rows X*256 + wid*32 + r32
    const int pi = X*256 + wid*32 + r32;
    const bf16x8 at = A8[pi*4 + half];
    const bf16x8 an = A8[pi*4 + 2 + half];

    f32x16 Z;
    #pragma unroll
    for (int k = 0; k < 16; ++k) Z[k] = 0.0f;

    // int32 B addressing: point stride 4 frags; j-tile stride 128; super-tile 1024
    const int base = J*1024 + r32*4 + half;

    // prefetch rotation in named registers
    bf16x8 btf = B8[base];
    bf16x8 bnf = B8[base + 2];

    float ts0 = 0.0f, ts1 = 0.0f;
    #pragma unroll 2
    for (int jt = 0; jt < 8; ++jt) {
        int nofs = base + ((jt < 7) ? (jt + 1) : jt) * 128;   // clamped redundant last
        bf16x8 nbt = B8[nofs];
        bf16x8 nbn = B8[nofs + 2];

        f32x16 ct = __builtin_amdgcn_mfma_f32_32x32x16_bf16(at, btf, Z, 0, 0, 0);
        f32x16 cn = __builtin_amdgcn_mfma_f32_32x32x16_bf16(an, bnf, Z, 0, 0, 0);

        // batched rcp: one v_rcp per 4 pairs; two independent partial chains
        #pragma unroll
        for (int g = 0; g < 4; ++g) {
            float t0 = ct[4*g+0], t1 = ct[4*g+1], t2 = ct[4*g+2], t3 = ct[4*g+3];
            float q0 = t0*t0, q1 = t1*t1, q2 = t2*t2, q3 = t3*t3;
            float s01 = q0*q1, s23 = q2*q3;
            float r   = __builtin_amdgcn_rcpf(s01*s23);
            float u   = __builtin_fmaf(cn[4*g+1], q0, cn[4*g+0]*q1);
            float v   = __builtin_fmaf(cn[4*g+3], q2, cn[4*g+2]*q3);
            float num = __builtin_fmaf(v, s01, u*s23);
            if (g & 1) ts1 = __builtin_fmaf(num, r, ts1);
            else       ts0 = __builtin_fmaf(num, r, ts0);
        }

        btf = nbt; bnf = nbn;
    }
    float acc = w * (ts0 + ts1);

    // wave shuffle reduce -> 8 partials -> one atomic per block
    for (int off = 32; off; off >>= 1) acc += __shfl_down(acc, off, 64);
    __shared__ float partial[8];
    if ((tid & 63) == 0) partial[wid] = acc;
    __syncthreads();
    if (tid == 0) {
        float s = ((partial[0] + partial[1]) + (partial[2] + partial[3]))
                + ((partial[4] + partial[5]) + (partial[6] + partial[7]));
        atomicAdd(out, s);
    }
}

extern "C" void kernel_launch(void* const* d_in, const int* in_sizes, int n_in,
                              void* d_out, int out_size, void* d_ws, size_t ws_size,
                              hipStream_t stream) {
    const float* sv = (const float*)d_in[0];
    const int*   si = (const int*)d_in[1];
    const float* tv = (const float*)d_in[2];
    const int*   ti = (const int*)d_in[3];
    const float* rn = (const float*)d_in[4];
    const float* rc = (const float*)d_in[5];
    float* out = (float*)d_out;
    u16*   ws  = (u16*)d_ws;                      // 2 x 24576 x 64 B = 3 MB features

    setup_feats<<<NPTS/256, 256, 0, stream>>>(sv, si, tv, ti, rn, rc, ws, out);
    dim3 grid(NSUP, NY);                          // 96 x 49 = 4704 blocks of 512
    energy_mfma<<<grid, 512, 0, stream>>>(ws, out);
}

// Round 11
// 118.580 us; speedup vs baseline: 3.7960x; 1.1280x over previous
//
#include <hip/hip_runtime.h>

#define NSEG 8192           // faces per set
#define NPTS (3 * NSEG)     // 24576 unified points [S | T | R]
#define NSUP 96             // 256-point super-tiles (32 per segment)
#define NXB  192            // 2 blocks (128 i-rows each) per super-tile
#define NYG  13             // y-groups: g<12 -> Y=4g..4g+3; g==12 -> Y=48

typedef short bf16x8 __attribute__((ext_vector_type(8)));   // 8 bf16 (4 VGPRs)
typedef float f32x16 __attribute__((ext_vector_type(16)));  // 16 fp32 acc
typedef unsigned short u16;

__device__ __forceinline__ u16 f2bf(float x) {              // RNE f32 -> bf16 bits
    unsigned u = __builtin_bit_cast(unsigned, x);
    return (u16)((u + 0x7FFFu + ((u >> 16) & 1u)) >> 16);
}
__device__ __forceinline__ float bf2f(u16 h) {
    unsigned u = ((unsigned)h) << 16;
    return __builtin_bit_cast(float, u);
}

__device__ __forceinline__ void compute_point(
    int seg, int f,
    const float* __restrict__ sv, const int* __restrict__ si,
    const float* __restrict__ tv, const int* __restrict__ ti,
    const float* __restrict__ rn, const float* __restrict__ rc,
    float& cx, float& cy, float& cz, float& nx, float& ny, float& nz)
{
    if (seg == 2) {
        nx = rn[3*f];   ny = rn[3*f+1]; nz = rn[3*f+2];
        cx = rc[3*f];   cy = rc[3*f+1]; cz = rc[3*f+2];
    } else {
        const float* v  = (seg == 0) ? sv : tv;
        const int*   nd = (seg == 0) ? si : ti;
        int i0 = nd[3*f], i1 = nd[3*f+1], i2 = nd[3*f+2];
        float ax = v[3*i0], ay = v[3*i0+1], az = v[3*i0+2];
        float bx = v[3*i1], by = v[3*i1+1], bz = v[3*i1+2];
        float gx = v[3*i2], gy = v[3*i2+1], gz = v[3*i2+2];
        float ux = ax-bx, uy = ay-by, uz = az-bz;
        float wx = gx-bx, wy = gy-by, wz = gz-bz;
        nx = 0.5f*(uy*wz - uz*wy);
        ny = 0.5f*(uz*wx - ux*wz);
        nz = 0.5f*(ux*wy - uy*wx);
        cx = (ax+bx+gx)*(1.0f/3.0f);
        cy = (ay+by+gy)*(1.0f/3.0f);
        cz = (az+bz+gz)*(1.0f/3.0f);
    }
}

// Feature rows (K=16 bf16), hi/lo split: t = A_t . B_t = 1+|ci-cj|^2 (~1e-3 abs err).
// Interleaved records: A-side point = {at[16], an[16]} (64 B), B-side = {bt[16], bn[16]}.
__global__ void setup_feats(const float* __restrict__ sv, const int* __restrict__ si,
                            const float* __restrict__ tv, const int* __restrict__ ti,
                            const float* __restrict__ rn, const float* __restrict__ rc,
                            u16* __restrict__ ws, float* __restrict__ out) {
    int p = blockIdx.x * 256 + threadIdx.x;
    if (p == 0) out[0] = 0.0f;          // d_out poisoned 0xAA before every launch
    if (p >= NPTS) return;
    int seg = p >> 13, f = p & (NSEG - 1);
    float cx, cy, cz, nx, ny, nz;
    compute_point(seg, f, sv, si, tv, ti, rn, rc, cx, cy, cz, nx, ny, nz);

    const u16 ONE = 0x3F80;
    float s = cx*cx + cy*cy + cz*cz;
    u16 chx = f2bf(cx), chy = f2bf(cy), chz = f2bf(cz);
    u16 clx = f2bf(cx - bf2f(chx)), cly = f2bf(cy - bf2f(chy)), clz = f2bf(cz - bf2f(chz));
    u16 sh  = f2bf(s);
    u16 sl  = f2bf(s - bf2f(sh));
    u16 m2hx = f2bf(-2.0f*bf2f(chx)), m2hy = f2bf(-2.0f*bf2f(chy)), m2hz = f2bf(-2.0f*bf2f(chz));
    u16 m2lx = f2bf(-2.0f*bf2f(clx)), m2ly = f2bf(-2.0f*bf2f(cly)), m2lz = f2bf(-2.0f*bf2f(clz));
    u16 nhx = f2bf(nx), nhy = f2bf(ny), nhz = f2bf(nz);
    u16 nlx = f2bf(nx - bf2f(nhx)), nly = f2bf(ny - bf2f(nhy)), nlz = f2bf(nz - bf2f(nhz));

    u16 at[16] = {chx,chy,chz, clx,cly,clz, chx,chy,chz, sh, sl, ONE, ONE, ONE, 0, 0};
    u16 bt[16] = {m2hx,m2hy,m2hz, m2hx,m2hy,m2hz, m2lx,m2ly,m2lz, ONE, ONE, sh, sl, ONE, 0, 0};
    u16 an[16] = {nhx,nhy,nhz, nlx,nly,nlz, nhx,nhy,nhz, 0,0,0,0,0,0,0};
    u16 bn[16] = {nhx,nhy,nhz, nhx,nhy,nhz, nlx,nly,nlz, 0,0,0,0,0,0,0};

    bf16x8* A8 = (bf16x8*)ws;            // A-record: frags [at0 at1 an0 an1] per point
    bf16x8* B8 = A8 + (size_t)NPTS*4;    // B-record: frags [bt0 bt1 bn0 bn1] per point
    bf16x8 v0, v1, v2, v3;
    #pragma unroll
    for (int k = 0; k < 8; ++k) { v0[k] = (short)at[k]; v1[k] = (short)at[k+8];
                                  v2[k] = (short)an[k]; v3[k] = (short)an[k+8]; }
    A8[(size_t)p*4+0] = v0; A8[(size_t)p*4+1] = v1; A8[(size_t)p*4+2] = v2; A8[(size_t)p*4+3] = v3;
    #pragma unroll
    for (int k = 0; k < 8; ++k) { v0[k] = (short)bt[k]; v1[k] = (short)bt[k+8];
                                  v2[k] = (short)bn[k]; v3[k] = (short)bn[k+8]; }
    B8[(size_t)p*4+0] = v0; B8[(size_t)p*4+1] = v1; B8[(size_t)p*4+2] = v2; B8[(size_t)p*4+3] = v3;
}

// Symmetric-pair kernel, consolidated j-work (R9 fix: 8 tiles/block starved the
// pipeline with per-block startup; now 32 tiles/wave like the 425-cyc/tile R6).
// Wrapped map over 256-pt super-tiles: (I,J) = (X, (X+Y)%96); mult = 2 except
// Y==0 (diagonal, once) and Y==48 (hit from both ends) -> 96+96+96*47*2 = 96^2. ✓
// Block = 256 thr = 4 waves x 32 i-rows (i-base = X*256 + (bx&1)*128), covering
// 4 consecutive Y values (g<12) or just Y=48 (g==12); 8 j-tiles per Y.
__launch_bounds__(256, 3)
__global__ void energy_mfma(const u16* __restrict__ ws, float* __restrict__ out) {
    const int tid  = threadIdx.x;
    const int lane = tid & 63, wid = tid >> 6;
    const int half = lane >> 5, r32 = lane & 31;

    const int bx = blockIdx.x;                // 0..191
    const int X  = bx >> 1;                   // super-tile row 0..95
    const int g  = blockIdx.y;                // 0..12
    const int y0  = (g < 12) ? 4*g : 48;
    const int ycnt = (g < 12) ? 4 : 1;
    const int gi = X >> 5;                    // 32 super-tiles per segment

    const float Wt[9] = {1.8f, -0.8f, -1.0f,
                        -0.8f,  1.8f, -1.0f,
                        -1.0f, -1.0f,  2.0f};

    const bf16x8* A8 = (const bf16x8*)ws;
    const bf16x8* B8 = A8 + (size_t)NPTS*4;

    // one persistent 32-row i-tile per wave: rows X*256 + (bx&1)*128 + wid*32 + r32
    const int pi = X*256 + (bx & 1)*128 + wid*32 + r32;
    const bf16x8 at = A8[pi*4 + half];
    const bf16x8 an = A8[pi*4 + 2 + half];

    f32x16 Z;
    #pragma unroll
    for (int k = 0; k < 16; ++k) Z[k] = 0.0f;

    const int lofs = r32*4 + half;            // per-lane frag offset within a j-tile

    float acc = 0.0f;
    for (int yy = 0; yy < ycnt; ++yy) {
        const int y = y0 + yy;
        int J = X + y; if (J >= NSUP) J -= NSUP;
        const float mult = (y == 0 || y == 48) ? 1.0f : 2.0f;
        const float w = Wt[gi*3 + (J >> 5)] * mult;   // block-uniform per y

        // int32 B addressing: point stride 4 frags; j-tile stride 128; super-tile 1024
        const int base = J*1024 + lofs;

        // prefetch rotation in named registers
        bf16x8 btf = B8[base];
        bf16x8 bnf = B8[base + 2];

        float ts0 = 0.0f, ts1 = 0.0f;
        #pragma unroll 2
        for (int jt = 0; jt < 8; ++jt) {
            int nofs = base + ((jt < 7) ? (jt + 1) : jt) * 128;  // clamped redundant last
            bf16x8 nbt = B8[nofs];
            bf16x8 nbn = B8[nofs + 2];

            f32x16 ct = __builtin_amdgcn_mfma_f32_32x32x16_bf16(at, btf, Z, 0, 0, 0);
            f32x16 cn = __builtin_amdgcn_mfma_f32_32x32x16_bf16(an, bnf, Z, 0, 0, 0);

            // batched rcp: one v_rcp per 4 pairs; two independent partial chains
            #pragma unroll
            for (int gq = 0; gq < 4; ++gq) {
                float t0 = ct[4*gq+0], t1 = ct[4*gq+1], t2 = ct[4*gq+2], t3 = ct[4*gq+3];
                float q0 = t0*t0, q1 = t1*t1, q2 = t2*t2, q3 = t3*t3;
                float s01 = q0*q1, s23 = q2*q3;
                float r   = __builtin_amdgcn_rcpf(s01*s23);
                float u   = __builtin_fmaf(cn[4*gq+1], q0, cn[4*gq+0]*q1);
                float v   = __builtin_fmaf(cn[4*gq+3], q2, cn[4*gq+2]*q3);
                float num = __builtin_fmaf(v, s01, u*s23);
                if (gq & 1) ts1 = __builtin_fmaf(num, r, ts1);
                else        ts0 = __builtin_fmaf(num, r, ts0);
            }

            btf = nbt; bnf = nbn;
        }
        acc = __builtin_fmaf(w, ts0 + ts1, acc);
    }

    // wave shuffle reduce -> 4 partials -> one atomic per block
    for (int off = 32; off; off >>= 1) acc += __shfl_down(acc, off, 64);
    __shared__ float partial[4];
    if ((tid & 63) == 0) partial[wid] = acc;
    __syncthreads();
    if (tid == 0)
        atomicAdd(out, (partial[0] + partial[1]) + (partial[2] + partial[3]));
}

extern "C" void kernel_launch(void* const* d_in, const int* in_sizes, int n_in,
                              void* d_out, int out_size, void* d_ws, size_t ws_size,
                              hipStream_t stream) {
    const float* sv = (const float*)d_in[0];
    const int*   si = (const int*)d_in[1];
    const float* tv = (const float*)d_in[2];
    const int*   ti = (const int*)d_in[3];
    const float* rn = (const float*)d_in[4];
    const float* rc = (const float*)d_in[5];
    float* out = (float*)d_out;
    u16*   ws  = (u16*)d_ws;                      // 2 x 24576 x 64 B = 3 MB features

    setup_feats<<<NPTS/256, 256, 0, stream>>>(sv, si, tv, ti, rn, rc, ws, out);
    dim3 grid(NXB, NYG);                          // 192 x 13 = 2496 blocks of 256
    energy_mfma<<<grid, 256, 0, stream>>>(ws, out);
}